// Round 3
// baseline (148.361 us; speedup 1.0000x reference)
//
#include <hip/hip_runtime.h>
#include <stdint.h>

// MPS chain contraction, B=32768, L=256, D=16.
// R10: register-direct frags + register phi, ZERO main-loop barriers.
//   R7/R8 A/B showed counted-vmcnt pipelining == full-drain __syncthreads
//   (60us both) -> not latency-bound; theory: per-CU global_load_lds DMA
//   service (~40KB/epoch at ~18B/cy ~= 2250cy) was the wall.
//   Now: pair frags are loaded straight into VGPRs (4x global_load_dwordx4
//   per pair, per-lane ws layout IS the A-fragment), 2-pair prefetch in
//   named regs; phi windows loaded to VGPRs with the old DMA lane map and
//   the 8 per-chunk coefficients pulled via ds_bpermute from lanes n+16*qt.
//   No LDS staging, no barriers, no manual waitcnt -- all deps are register
//   dataflow the compiler tracks. LDS = 5KB epilogue buffer only.

typedef short  bf16x8 __attribute__((ext_vector_type(8)));
typedef float  f32x4  __attribute__((ext_vector_type(4)));
typedef int    i32x4  __attribute__((ext_vector_type(4)));
typedef unsigned int u32;

#define NPF 64
#define NPB 63
#define BWD_OFF (NPF*4*64)   // i32x4 units

#define PACK_HI(hi, lo) ((int)__builtin_amdgcn_perm((u32)(hi), (u32)(lo), 0x07060302u))

__device__ __forceinline__ u32 rne_bump(u32 u){ return u + 0x7FFFu + ((u >> 16) & 1u); }

// Pair-fragment table: blocks 0..63 fwd (j=bid), 64..126 bwd (j=bid-64).
// fwd: G[m][cq] = sum_r Ca[cq][p][r]*Cb[r][q][m],  Ca=cm[2j], Cb=cm[2j+1]
// bwd: G[m][cq] = sum_r Ca[m][p][r]*Cb[r][q][cq],  Ca=cm[252-2j], Cb=cm[253-2j]
// lane (m=lane&15, g=lane>>4) packs cols 4g..4g+3 hi (dw0,1) and lo (dw2,3).
__global__ void build_pair_frags(const float* __restrict__ cm, i32x4* __restrict__ ws)
{
  __shared__ float Ca[512], Cb[512];   // [x][p][y] = cm[t][x][p][y]
  const int bid = blockIdx.x;
  const bool fwd = bid < NPF;
  const int j  = fwd ? bid : bid - NPF;
  const int ta = fwd ? 2*j     : 252 - 2*j;
  const int tb = fwd ? 2*j + 1 : 253 - 2*j;
  {
    const float* A = cm + ta*512;
    const float* B = cm + tb*512;
    for (int i = threadIdx.x; i < 512; i += 256){ Ca[i] = A[i]; Cb[i] = B[i]; }
  }
  __syncthreads();
  const int f    = threadIdx.x >> 6;    // combo p*2+q
  const int lane = threadIdx.x & 63;
  const int m    = lane & 15;
  const int g    = lane >> 4;
  const int p    = f >> 1, q = f & 1;
  u32 hi[4], lo[4];
  #pragma unroll
  for (int x = 0; x < 4; ++x){
    const int cq = 4*g + x;
    float acc = 0.f;
    #pragma unroll
    for (int r = 0; r < 16; ++r){
      const float a = fwd ? Ca[cq*32 + p*16 + r] : Ca[m*32 + p*16 + r];
      const float b = fwd ? Cb[r*32 + q*16 + m]  : Cb[r*32 + q*16 + cq];
      acc = fmaf(a, b, acc);
    }
    const u32 u  = __float_as_uint(acc);
    const u32 aa = rne_bump(u);
    const float hf = __uint_as_float(aa & 0xFFFF0000u);
    const u32 bb = rne_bump(__float_as_uint(acc - hf));
    hi[x] = aa >> 16; lo[x] = bb >> 16;
  }
  i32x4 w;
  w[0] = (int)(hi[0] | (hi[1] << 16));
  w[1] = (int)(hi[2] | (hi[3] << 16));
  w[2] = (int)(lo[0] | (lo[1] << 16));
  w[3] = (int)(lo[2] | (lo[3] << 16));
  ws[(fwd ? 0 : BWD_OFF) + (j*4 + f)*64 + lane] = w;
}

__global__ __launch_bounds__(256, 4) void mps_chain(
  const float* __restrict__ phi,
  const float* __restrict__ core_first,
  const float* __restrict__ core_last,
  const float* __restrict__ bias,
  const i32x4* __restrict__ ws,
  float* __restrict__ out)
{
  const int lane = threadIdx.x & 63;
  const int wv   = threadIdx.x >> 6;
  const int b0   = blockIdx.x * 32;
  const int n    = lane & 15;            // sample column
  const int g    = lane >> 4;            // holds rows 4g..4g+3
  const int half = wv & 1;
  const int s_in = half*16 + n;
  const bool isFwd = (wv < 2);
  const int dirIdx = isFwd ? 0 : 1;

  __shared__ float red[64*20];           // epilogue reduction only (5 KB)

  const float* phiRow = phi + (size_t)(b0 + s_in) * 512;

  // phi register-load source (same lane map the old DMA used):
  // lane l covers sample (b0+16*half+(l&15)), window floats (l>>4)*4 .. +3
  const float* phiSrc = phi + (size_t)(b0 + 16*half + (lane & 15)) * 512
                            + (lane >> 4) * 4;

  const i32x4* wsD    = isFwd ? ws : (ws + BWD_OFF);
  const int    maxPr  = isFwd ? NPF - 1 : NPB - 1;
  const i32x4* wsLane = wsD + lane;      // + pr*256 + f*64 selects (pair, combo)

  // ds_bpermute byte addrs for the 3 qt-groups this direction needs.
  // value(f_idx) lives in lane (lane&15) + 16*qt (qt=f_idx>>2), elem f_idx&3.
  const int qtF  = isFwd ? 0 : 1;
  const int aQ   = ((lane & 15) + 16*qtF) << 2;
  const int adrA0 = isFwd ? aQ       : aQ + 64;   // fwd f2,f3 (qt0) | bwd f10,f11 (qt2)
  const int adrB0 = isFwd ? aQ + 64  : aQ + 128;  // fwd f4,f5 (qt1) | bwd f12,f13 (qt3)
  const int adrA1 = isFwd ? aQ + 64  : aQ;        // fwd f6,f7 (qt1) | bwd f6,f7  (qt1)
  const int adrB1 = isFwd ? aQ + 128 : aQ + 64;   // fwd f8,f9 (qt2) | bwd f8,f9  (qt2)

  float v[4];
  i32x4 bfr;

  auto make_bfrag = [&](){
    const u32 u0 = __float_as_uint(v[0]), u1 = __float_as_uint(v[1]);
    const u32 u2 = __float_as_uint(v[2]), u3 = __float_as_uint(v[3]);
    const float l0 = v[0] - __uint_as_float(u0 & 0xFFFF0000u);
    const float l1 = v[1] - __uint_as_float(u1 & 0xFFFF0000u);
    const float l2 = v[2] - __uint_as_float(u2 & 0xFFFF0000u);
    const float l3 = v[3] - __uint_as_float(u3 & 0xFFFF0000u);
    bfr[0] = PACK_HI(u1, u0);
    bfr[1] = PACK_HI(u3, u2);
    bfr[2] = PACK_HI(__float_as_uint(l1), __float_as_uint(l0));
    bfr[3] = PACK_HI(__float_as_uint(l3), __float_as_uint(l2));
  };

  auto pair_step = [&](const i32x4& G0, const i32x4& G1, const i32x4& G2,
                       const i32x4& G3, float2 cA, float2 cB){
    const float c00 = cA.x*cB.x, c01 = cA.x*cB.y;
    const float c10 = cA.y*cB.x, c11 = cA.y*cB.y;
    i32x4 sw; sw[0]=bfr[2]; sw[1]=bfr[3]; sw[2]=bfr[0]; sw[3]=bfr[1];
    const bf16x8 bh = __builtin_bit_cast(bf16x8, bfr);
    const bf16x8 bs = __builtin_bit_cast(bf16x8, sw);
    const f32x4 z = {0.f,0.f,0.f,0.f};
    __builtin_amdgcn_s_setprio(1);
    f32x4 a00 = __builtin_amdgcn_mfma_f32_16x16x32_bf16(__builtin_bit_cast(bf16x8,G0), bh, z, 0,0,0);
    a00 = __builtin_amdgcn_mfma_f32_16x16x32_bf16(__builtin_bit_cast(bf16x8,G0), bs, a00, 0,0,0);
    f32x4 a01 = __builtin_amdgcn_mfma_f32_16x16x32_bf16(__builtin_bit_cast(bf16x8,G1), bh, z, 0,0,0);
    a01 = __builtin_amdgcn_mfma_f32_16x16x32_bf16(__builtin_bit_cast(bf16x8,G1), bs, a01, 0,0,0);
    f32x4 a10 = __builtin_amdgcn_mfma_f32_16x16x32_bf16(__builtin_bit_cast(bf16x8,G2), bh, z, 0,0,0);
    a10 = __builtin_amdgcn_mfma_f32_16x16x32_bf16(__builtin_bit_cast(bf16x8,G2), bs, a10, 0,0,0);
    f32x4 a11 = __builtin_amdgcn_mfma_f32_16x16x32_bf16(__builtin_bit_cast(bf16x8,G3), bh, z, 0,0,0);
    a11 = __builtin_amdgcn_mfma_f32_16x16x32_bf16(__builtin_bit_cast(bf16x8,G3), bs, a11, 0,0,0);
    __builtin_amdgcn_s_setprio(0);
    #pragma unroll
    for (int i2 = 0; i2 < 4; ++i2)
      v[i2] = c00*a00[i2] + c01*a01[i2] + c10*a10[i2] + c11*a11[i2];
    make_bfrag();
  };

  // ---- init chain vector ----
  if (isFwd){
    const float2 ph0 = *(const float2*)phiRow;               // phi[0]
    #pragma unroll
    for (int reg = 0; reg < 4; ++reg){
      const int r = g*4 + reg;
      v[reg] = ph0.x * core_first[r] + ph0.y * core_first[16 + r];
    }
  } else {
    const float2 phL2 = *(const float2*)(phiRow + 510);      // phi[255]
    #pragma unroll
    for (int reg = 0; reg < 4; ++reg){
      const int r = g*4 + reg;
      v[reg] = phL2.x * core_last[2*r] + phL2.y * core_last[2*r + 1];
    }
  }
  make_bfrag();

  // ---- register prefetch state ----
  i32x4 A0, A1, A2, A3;     // even pair (2c)
  i32x4 B0, B1, B2, B3;     // odd pair (2c+1)
  f32x4 phiC, phiN;         // phi windows, chunks c and c+1

  {
    const i32x4* s = wsLane;                       // pair 0
    A0 = s[0]; A1 = s[64]; A2 = s[128]; A3 = s[192];
  }
  {
    const i32x4* s = wsLane + 256;                 // pair 1
    B0 = s[0]; B1 = s[64]; B2 = s[128]; B3 = s[192];
  }
  phiC = *(const f32x4*)(phiSrc + (isFwd ? 0 : 496));   // chunk 0 window
  phiN = *(const f32x4*)(phiSrc + (isFwd ? 8 : 488));   // chunk 1 window

  #pragma unroll 1
  for (int c = 0; c < 32; ++c){
    // ---- chunk coefficients via cross-lane pulls from phiC ----
    auto S = [&](int e, int adr)->float {
      return __int_as_float(__builtin_amdgcn_ds_bpermute(adr, __float_as_int(phiC[e])));
    };
    const float2 xA0 = make_float2(S(2, adrA0), S(3, adrA0));
    const float2 xB0 = make_float2(S(0, adrB0), S(1, adrB0));
    const float2 xA1 = make_float2(S(2, adrA1), S(3, adrA1));
    const float2 xB1 = make_float2(S(0, adrB1), S(1, adrB1));

    // ---- pair 2c ----
    pair_step(A0, A1, A2, A3, xA0, xB0);
    {
      const int j = 2*c + 2;
      const i32x4* s = wsLane + (j > maxPr ? maxPr : j) * 256;
      A0 = s[0]; A1 = s[64]; A2 = s[128]; A3 = s[192];
    }

    // ---- pair 2c+1 ----
    if (isFwd || (2*c + 1) < NPB)
      pair_step(B0, B1, B2, B3, xA1, xB1);
    {
      const int j = 2*c + 3;
      const i32x4* s = wsLane + (j > maxPr ? maxPr : j) * 256;
      B0 = s[0]; B1 = s[64]; B2 = s[128]; B3 = s[192];
    }

    // ---- phi rotate + prefetch chunk c+2 ----
    phiC = phiN;
    {
      const int cc = (c + 2 > 31) ? 31 : (c + 2);
      phiN = *(const f32x4*)(phiSrc + (isFwd ? 8*cc : 496 - 8*cc));
    }
  }

  // ---- epilogue: cross-wave reduction ----
  *(float4*)&red[(dirIdx*32 + s_in)*20 + 4*g] =
      make_float4(v[0], v[1], v[2], v[3]);
  __syncthreads();
  if (threadIdx.x < 32){
    const int s = threadIdx.x;
    float acc = bias[0];
    #pragma unroll
    for (int qq = 0; qq < 16; ++qq)
      acc += red[s*20 + qq] * red[(32 + s)*20 + qq];
    out[b0 + s] = acc;
  }
}

extern "C" void kernel_launch(void* const* d_in, const int* in_sizes, int n_in,
                              void* d_out, int out_size, void* d_ws, size_t ws_size,
                              hipStream_t stream)
{
  const float* phi  = (const float*)d_in[0];  // [32768,256,2]
  const float* cf   = (const float*)d_in[1];  // [2,16]
  const float* cm   = (const float*)d_in[2];  // [254,16,2,16]
  const float* cl   = (const float*)d_in[3];  // [16,2]
  const float* bias = (const float*)d_in[4];  // scalar
  i32x4* ws = (i32x4*)d_ws;                   // (64+63)*4*64*16B = 508 KB

  build_pair_frags<<<NPF + NPB, 256, 0, stream>>>(cm, ws);
  mps_chain<<<1024, 256, 0, stream>>>(phi, cf, cl, bias, ws, (float*)d_out);
}

// Round 4
// 145.454 us; speedup vs baseline: 1.0200x; 1.0200x over previous
//
#include <hip/hip_runtime.h>
#include <stdint.h>

// MPS chain contraction, B=32768, L=256, D=16.
// R11: 4 chains per wave -> 4x A-operand (pair-fragment) reuse.
//   Traffic accounting across R7/R8/R10 showed the binding constraint is
//   frag RE-READ volume through L2 (R7: 520MB->60us; R10: 1.04GB->74us;
//   both ~9-14 TB/s effective), not latency (R8 counted-vmcnt was a no-op)
//   and not the DMA engine. Fix: each wave now carries FOUR independent
//   16-sample chains and loads each pair's 4KB fragment set into registers
//   ONCE for all four B-operands: 1024 waves x 64 pairs x 4KB = 268MB.
//   Grid 256 blocks x 256 thr (1 block/CU, 1 wave/SIMD); latency hiding
//   comes from 4-chain intra-wave ILP; main loop is pure register dataflow
//   (no LDS staging, no barriers, no manual waitcnt).
//   __launch_bounds__(256,1): no pressure motive to sink prefetches
//   (R10's VGPR=40 proved sinking); prefetch clusters pinned with
//   sched_barrier(0).

typedef short  bf16x8 __attribute__((ext_vector_type(8)));
typedef float  f32x4  __attribute__((ext_vector_type(4)));
typedef int    i32x4  __attribute__((ext_vector_type(4)));
typedef unsigned int u32;

#define NPF 64
#define NPB 63
#define BWD_OFF (NPF*4*64)   // i32x4 units

#define PACK_HI(hi, lo) ((int)__builtin_amdgcn_perm((u32)(hi), (u32)(lo), 0x07060302u))

__device__ __forceinline__ u32 rne_bump(u32 u){ return u + 0x7FFFu + ((u >> 16) & 1u); }

// Pair-fragment table: blocks 0..63 fwd (j=bid), 64..126 bwd (j=bid-64).
// fwd: G[m][cq] = sum_r Ca[cq][p][r]*Cb[r][q][m],  Ca=cm[2j], Cb=cm[2j+1]
// bwd: G[m][cq] = sum_r Ca[m][p][r]*Cb[r][q][cq],  Ca=cm[252-2j], Cb=cm[253-2j]
// lane (m=lane&15, g=lane>>4) packs cols 4g..4g+3 hi (dw0,1) and lo (dw2,3).
__global__ void build_pair_frags(const float* __restrict__ cm, i32x4* __restrict__ ws)
{
  __shared__ float Ca[512], Cb[512];   // [x][p][y] = cm[t][x][p][y]
  const int bid = blockIdx.x;
  const bool fwd = bid < NPF;
  const int j  = fwd ? bid : bid - NPF;
  const int ta = fwd ? 2*j     : 252 - 2*j;
  const int tb = fwd ? 2*j + 1 : 253 - 2*j;
  {
    const float* A = cm + ta*512;
    const float* B = cm + tb*512;
    for (int i = threadIdx.x; i < 512; i += 256){ Ca[i] = A[i]; Cb[i] = B[i]; }
  }
  __syncthreads();
  const int f    = threadIdx.x >> 6;    // combo p*2+q
  const int lane = threadIdx.x & 63;
  const int m    = lane & 15;
  const int g    = lane >> 4;
  const int p    = f >> 1, q = f & 1;
  u32 hi[4], lo[4];
  #pragma unroll
  for (int x = 0; x < 4; ++x){
    const int cq = 4*g + x;
    float acc = 0.f;
    #pragma unroll
    for (int r = 0; r < 16; ++r){
      const float a = fwd ? Ca[cq*32 + p*16 + r] : Ca[m*32 + p*16 + r];
      const float b = fwd ? Cb[r*32 + q*16 + m]  : Cb[r*32 + q*16 + cq];
      acc = fmaf(a, b, acc);
    }
    const u32 u  = __float_as_uint(acc);
    const u32 aa = rne_bump(u);
    const float hf = __uint_as_float(aa & 0xFFFF0000u);
    const u32 bb = rne_bump(__float_as_uint(acc - hf));
    hi[x] = aa >> 16; lo[x] = bb >> 16;
  }
  i32x4 w;
  w[0] = (int)(hi[0] | (hi[1] << 16));
  w[1] = (int)(hi[2] | (hi[3] << 16));
  w[2] = (int)(lo[0] | (lo[1] << 16));
  w[3] = (int)(lo[2] | (lo[3] << 16));
  ws[(fwd ? 0 : BWD_OFF) + (j*4 + f)*64 + lane] = w;
}

__device__ __forceinline__ void make_bfrag(const float (&v)[4], i32x4 &bfr)
{
  const u32 u0 = __float_as_uint(v[0]), u1 = __float_as_uint(v[1]);
  const u32 u2 = __float_as_uint(v[2]), u3 = __float_as_uint(v[3]);
  const float l0 = v[0] - __uint_as_float(u0 & 0xFFFF0000u);
  const float l1 = v[1] - __uint_as_float(u1 & 0xFFFF0000u);
  const float l2 = v[2] - __uint_as_float(u2 & 0xFFFF0000u);
  const float l3 = v[3] - __uint_as_float(u3 & 0xFFFF0000u);
  bfr[0] = PACK_HI(u1, u0);
  bfr[1] = PACK_HI(u3, u2);
  bfr[2] = PACK_HI(__float_as_uint(l1), __float_as_uint(l0));
  bfr[3] = PACK_HI(__float_as_uint(l3), __float_as_uint(l2));
}

__device__ __forceinline__ void pair_step(
    const i32x4 &G0, const i32x4 &G1, const i32x4 &G2, const i32x4 &G3,
    float2 cA, float2 cB, float (&v)[4], i32x4 &bfr)
{
  const float c00 = cA.x*cB.x, c01 = cA.x*cB.y;
  const float c10 = cA.y*cB.x, c11 = cA.y*cB.y;
  i32x4 sw; sw[0]=bfr[2]; sw[1]=bfr[3]; sw[2]=bfr[0]; sw[3]=bfr[1];
  const bf16x8 bh = __builtin_bit_cast(bf16x8, bfr);
  const bf16x8 bs = __builtin_bit_cast(bf16x8, sw);
  const f32x4 z = {0.f,0.f,0.f,0.f};
  f32x4 a00 = __builtin_amdgcn_mfma_f32_16x16x32_bf16(__builtin_bit_cast(bf16x8,G0), bh, z, 0,0,0);
  a00 = __builtin_amdgcn_mfma_f32_16x16x32_bf16(__builtin_bit_cast(bf16x8,G0), bs, a00, 0,0,0);
  f32x4 a01 = __builtin_amdgcn_mfma_f32_16x16x32_bf16(__builtin_bit_cast(bf16x8,G1), bh, z, 0,0,0);
  a01 = __builtin_amdgcn_mfma_f32_16x16x32_bf16(__builtin_bit_cast(bf16x8,G1), bs, a01, 0,0,0);
  f32x4 a10 = __builtin_amdgcn_mfma_f32_16x16x32_bf16(__builtin_bit_cast(bf16x8,G2), bh, z, 0,0,0);
  a10 = __builtin_amdgcn_mfma_f32_16x16x32_bf16(__builtin_bit_cast(bf16x8,G2), bs, a10, 0,0,0);
  f32x4 a11 = __builtin_amdgcn_mfma_f32_16x16x32_bf16(__builtin_bit_cast(bf16x8,G3), bh, z, 0,0,0);
  a11 = __builtin_amdgcn_mfma_f32_16x16x32_bf16(__builtin_bit_cast(bf16x8,G3), bs, a11, 0,0,0);
  #pragma unroll
  for (int i2 = 0; i2 < 4; ++i2)
    v[i2] = c00*a00[i2] + c01*a01[i2] + c10*a10[i2] + c11*a11[i2];
  make_bfrag(v, bfr);
}

__global__ __launch_bounds__(256, 1) void mps_chain(
  const float* __restrict__ phi,
  const float* __restrict__ core_first,
  const float* __restrict__ core_last,
  const float* __restrict__ bias,
  const i32x4* __restrict__ ws,
  float* __restrict__ out)
{
  const int lane = threadIdx.x & 63;
  const int wv   = threadIdx.x >> 6;
  const int n    = lane & 15;            // sample column within a group
  const int g    = lane >> 4;            // matrix row group / phi window quarter
  const bool isFwd = (wv < 2);
  const int dirIdx = isFwd ? 0 : 1;
  // wave covers 64 samples: 4 chains x 16
  const int sb   = blockIdx.x * 128 + (wv & 1) * 64;

  __shared__ float red[256*20];          // epilogue reduction only (20 KB)

  const i32x4* wsD    = isFwd ? ws : (ws + BWD_OFF);
  const int    maxPr  = isFwd ? NPF - 1 : NPB - 1;
  const i32x4* wsLane = wsD + lane;      // + pr*256 + f*64 selects (pair, combo)

  // phi window source base (lane map: sample = sb+16k+(lane&15),
  // window floats (lane>>4)*4 .. +3); group k adds k*16*512 floats.
  const float* phiSrc0 = phi + (size_t)(sb + n) * 512 + g * 4;

  // ds_bpermute byte addrs (identical per group; verified in R10):
  // value(window float qt*4+e) lives in lane n+16*qt, elem e.
  const int qtF  = isFwd ? 0 : 1;
  const int aQ   = ((lane & 15) + 16*qtF) << 2;
  const int adrA0 = isFwd ? aQ       : aQ + 64;   // fwd fl2,3  | bwd fl10,11
  const int adrB0 = isFwd ? aQ + 64  : aQ + 128;  // fwd fl4,5  | bwd fl12,13
  const int adrA1 = isFwd ? aQ + 64  : aQ;        // fwd fl6,7  | bwd fl6,7
  const int adrB1 = isFwd ? aQ + 128 : aQ + 64;   // fwd fl8,9  | bwd fl8,9

  // ---- chain state: 4 independent chains ----
  float vch[4][4];
  i32x4 bfr[4];

  #pragma unroll
  for (int k = 0; k < 4; ++k){
    const float* pr = phi + (size_t)(sb + 16*k + n) * 512;
    if (isFwd){
      const float2 p0 = *(const float2*)pr;                 // phi[0]
      #pragma unroll
      for (int reg = 0; reg < 4; ++reg){
        const int r = g*4 + reg;
        vch[k][reg] = p0.x * core_first[r] + p0.y * core_first[16 + r];
      }
    } else {
      const float2 pL = *(const float2*)(pr + 510);         // phi[255]
      #pragma unroll
      for (int reg = 0; reg < 4; ++reg){
        const int r = g*4 + reg;
        vch[k][reg] = pL.x * core_last[2*r] + pL.y * core_last[2*r + 1];
      }
    }
    make_bfrag(vch[k], bfr[k]);
  }

  // ---- register prefetch state ----
  i32x4 GA0, GA1, GA2, GA3;   // even pair (2c)
  i32x4 GB0, GB1, GB2, GB3;   // odd pair (2c+1)
  f32x4 phiC[4], phiN[4];     // per-group phi windows, chunks c and c+1

  { const i32x4* s = wsLane;        GA0=s[0]; GA1=s[64]; GA2=s[128]; GA3=s[192]; }
  { const i32x4* s = wsLane + 256;  GB0=s[0]; GB1=s[64]; GB2=s[128]; GB3=s[192]; }
  #pragma unroll
  for (int k = 0; k < 4; ++k){
    const float* ps = phiSrc0 + (size_t)k * 16 * 512;
    phiC[k] = *(const f32x4*)(ps + (isFwd ? 0 : 496));
    phiN[k] = *(const f32x4*)(ps + (isFwd ? 8 : 488));
  }
  __builtin_amdgcn_sched_barrier(0);

  #pragma unroll 1
  for (int c = 0; c < 32; ++c){
    // ---- chunk coefficients for all 4 groups (cross-lane pulls) ----
    float2 cA0[4], cB0[4], cA1[4], cB1[4];
    #pragma unroll
    for (int k = 0; k < 4; ++k){
      #define SPULL(e, adr) __int_as_float(__builtin_amdgcn_ds_bpermute((adr), __float_as_int(phiC[k][e])))
      cA0[k] = make_float2(SPULL(2, adrA0), SPULL(3, adrA0));
      cB0[k] = make_float2(SPULL(0, adrB0), SPULL(1, adrB0));
      cA1[k] = make_float2(SPULL(2, adrA1), SPULL(3, adrA1));
      cB1[k] = make_float2(SPULL(0, adrB1), SPULL(1, adrB1));
      #undef SPULL
    }

    // ---- pair 2c: 4 chains share GA ----
    #pragma unroll
    for (int k = 0; k < 4; ++k)
      pair_step(GA0, GA1, GA2, GA3, cA0[k], cB0[k], vch[k], bfr[k]);
    { const int j = 2*c + 2;
      const i32x4* s = wsLane + (j > maxPr ? maxPr : j) * 256;
      GA0=s[0]; GA1=s[64]; GA2=s[128]; GA3=s[192]; }
    __builtin_amdgcn_sched_barrier(0);

    // ---- pair 2c+1: 4 chains share GB ----
    if (isFwd || (2*c + 1) < NPB){
      #pragma unroll
      for (int k = 0; k < 4; ++k)
        pair_step(GB0, GB1, GB2, GB3, cA1[k], cB1[k], vch[k], bfr[k]);
    }
    { const int j = 2*c + 3;
      const i32x4* s = wsLane + (j > maxPr ? maxPr : j) * 256;
      GB0=s[0]; GB1=s[64]; GB2=s[128]; GB3=s[192]; }

    // ---- phi rotate + prefetch chunk c+2 ----
    #pragma unroll
    for (int k = 0; k < 4; ++k) phiC[k] = phiN[k];
    { const int cc = (c + 2 > 31) ? 31 : (c + 2);
      #pragma unroll
      for (int k = 0; k < 4; ++k){
        const float* ps = phiSrc0 + (size_t)k * 16 * 512;
        phiN[k] = *(const f32x4*)(ps + (isFwd ? 8*cc : 496 - 8*cc));
      } }
    __builtin_amdgcn_sched_barrier(0);
  }

  // ---- epilogue: cross-wave reduction ----
  #pragma unroll
  for (int k = 0; k < 4; ++k)
    *(float4*)&red[(dirIdx*128 + (wv & 1)*64 + 16*k + n)*20 + 4*g] =
        make_float4(vch[k][0], vch[k][1], vch[k][2], vch[k][3]);
  __syncthreads();
  if (threadIdx.x < 128){
    const int s = threadIdx.x;
    float acc = bias[0];
    #pragma unroll
    for (int qq = 0; qq < 16; ++qq)
      acc += red[s*20 + qq] * red[(128 + s)*20 + qq];
    out[blockIdx.x*128 + s] = acc;
  }
}

extern "C" void kernel_launch(void* const* d_in, const int* in_sizes, int n_in,
                              void* d_out, int out_size, void* d_ws, size_t ws_size,
                              hipStream_t stream)
{
  const float* phi  = (const float*)d_in[0];  // [32768,256,2]
  const float* cf   = (const float*)d_in[1];  // [2,16]
  const float* cm   = (const float*)d_in[2];  // [254,16,2,16]
  const float* cl   = (const float*)d_in[3];  // [16,2]
  const float* bias = (const float*)d_in[4];  // scalar
  i32x4* ws = (i32x4*)d_ws;                   // (64+63)*4*64*16B = 508 KB

  build_pair_frags<<<NPF + NPB, 256, 0, stream>>>(cm, ws);
  mps_chain<<<256, 256, 0, stream>>>(phi, cf, cl, bias, ws, (float*)d_out);
}

// Round 5
// 137.384 us; speedup vs baseline: 1.0799x; 1.0587x over previous
//
#include <hip/hip_runtime.h>
#include <stdint.h>

// MPS chain contraction, B=32768, L=256, D=16.
// R12: 2 chains/wave, 512 blocks -> 2 waves/SIMD + 536MB frag traffic.
//   Model from R7/R10/R11: (a) frag-fetch path ceiling ~14 TB/s (R10:
//   1.04GB/74us), (b) 1 wave/SIMD exposes all latency (R11: 50% issue,
//   76us at only 3.5 TB/s), (c) VALU-busy time ~24us invariant = issue
//   floor. R12 balances: 2-chain waves halve R10's traffic (536MB -> =38us
//   at the 14TB/s ceiling) while restoring 2 waves/SIMD for stall hiding.
//   Pure register dataflow (no LDS staging, no barriers, no waitcnt).

typedef short  bf16x8 __attribute__((ext_vector_type(8)));
typedef float  f32x4  __attribute__((ext_vector_type(4)));
typedef int    i32x4  __attribute__((ext_vector_type(4)));
typedef unsigned int u32;

#define NPF 64
#define NPB 63
#define BWD_OFF (NPF*4*64)   // i32x4 units

#define PACK_HI(hi, lo) ((int)__builtin_amdgcn_perm((u32)(hi), (u32)(lo), 0x07060302u))

__device__ __forceinline__ u32 rne_bump(u32 u){ return u + 0x7FFFu + ((u >> 16) & 1u); }

// Pair-fragment table: blocks 0..63 fwd (j=bid), 64..126 bwd (j=bid-64).
// fwd: G[m][cq] = sum_r Ca[cq][p][r]*Cb[r][q][m],  Ca=cm[2j], Cb=cm[2j+1]
// bwd: G[m][cq] = sum_r Ca[m][p][r]*Cb[r][q][cq],  Ca=cm[252-2j], Cb=cm[253-2j]
// lane (m=lane&15, g=lane>>4) packs cols 4g..4g+3 hi (dw0,1) and lo (dw2,3).
__global__ void build_pair_frags(const float* __restrict__ cm, i32x4* __restrict__ ws)
{
  __shared__ float Ca[512], Cb[512];   // [x][p][y] = cm[t][x][p][y]
  const int bid = blockIdx.x;
  const bool fwd = bid < NPF;
  const int j  = fwd ? bid : bid - NPF;
  const int ta = fwd ? 2*j     : 252 - 2*j;
  const int tb = fwd ? 2*j + 1 : 253 - 2*j;
  {
    const float* A = cm + ta*512;
    const float* B = cm + tb*512;
    for (int i = threadIdx.x; i < 512; i += 256){ Ca[i] = A[i]; Cb[i] = B[i]; }
  }
  __syncthreads();
  const int f    = threadIdx.x >> 6;    // combo p*2+q
  const int lane = threadIdx.x & 63;
  const int m    = lane & 15;
  const int g    = lane >> 4;
  const int p    = f >> 1, q = f & 1;
  u32 hi[4], lo[4];
  #pragma unroll
  for (int x = 0; x < 4; ++x){
    const int cq = 4*g + x;
    float acc = 0.f;
    #pragma unroll
    for (int r = 0; r < 16; ++r){
      const float a = fwd ? Ca[cq*32 + p*16 + r] : Ca[m*32 + p*16 + r];
      const float b = fwd ? Cb[r*32 + q*16 + m]  : Cb[r*32 + q*16 + cq];
      acc = fmaf(a, b, acc);
    }
    const u32 u  = __float_as_uint(acc);
    const u32 aa = rne_bump(u);
    const float hf = __uint_as_float(aa & 0xFFFF0000u);
    const u32 bb = rne_bump(__float_as_uint(acc - hf));
    hi[x] = aa >> 16; lo[x] = bb >> 16;
  }
  i32x4 w;
  w[0] = (int)(hi[0] | (hi[1] << 16));
  w[1] = (int)(hi[2] | (hi[3] << 16));
  w[2] = (int)(lo[0] | (lo[1] << 16));
  w[3] = (int)(lo[2] | (lo[3] << 16));
  ws[(fwd ? 0 : BWD_OFF) + (j*4 + f)*64 + lane] = w;
}

__device__ __forceinline__ void make_bfrag(const float (&v)[4], i32x4 &bfr)
{
  const u32 u0 = __float_as_uint(v[0]), u1 = __float_as_uint(v[1]);
  const u32 u2 = __float_as_uint(v[2]), u3 = __float_as_uint(v[3]);
  const float l0 = v[0] - __uint_as_float(u0 & 0xFFFF0000u);
  const float l1 = v[1] - __uint_as_float(u1 & 0xFFFF0000u);
  const float l2 = v[2] - __uint_as_float(u2 & 0xFFFF0000u);
  const float l3 = v[3] - __uint_as_float(u3 & 0xFFFF0000u);
  bfr[0] = PACK_HI(u1, u0);
  bfr[1] = PACK_HI(u3, u2);
  bfr[2] = PACK_HI(__float_as_uint(l1), __float_as_uint(l0));
  bfr[3] = PACK_HI(__float_as_uint(l3), __float_as_uint(l2));
}

__device__ __forceinline__ void pair_step(
    const i32x4 &G0, const i32x4 &G1, const i32x4 &G2, const i32x4 &G3,
    float2 cA, float2 cB, float (&v)[4], i32x4 &bfr)
{
  const float c00 = cA.x*cB.x, c01 = cA.x*cB.y;
  const float c10 = cA.y*cB.x, c11 = cA.y*cB.y;
  i32x4 sw; sw[0]=bfr[2]; sw[1]=bfr[3]; sw[2]=bfr[0]; sw[3]=bfr[1];
  const bf16x8 bh = __builtin_bit_cast(bf16x8, bfr);
  const bf16x8 bs = __builtin_bit_cast(bf16x8, sw);
  const f32x4 z = {0.f,0.f,0.f,0.f};
  f32x4 a00 = __builtin_amdgcn_mfma_f32_16x16x32_bf16(__builtin_bit_cast(bf16x8,G0), bh, z, 0,0,0);
  a00 = __builtin_amdgcn_mfma_f32_16x16x32_bf16(__builtin_bit_cast(bf16x8,G0), bs, a00, 0,0,0);
  f32x4 a01 = __builtin_amdgcn_mfma_f32_16x16x32_bf16(__builtin_bit_cast(bf16x8,G1), bh, z, 0,0,0);
  a01 = __builtin_amdgcn_mfma_f32_16x16x32_bf16(__builtin_bit_cast(bf16x8,G1), bs, a01, 0,0,0);
  f32x4 a10 = __builtin_amdgcn_mfma_f32_16x16x32_bf16(__builtin_bit_cast(bf16x8,G2), bh, z, 0,0,0);
  a10 = __builtin_amdgcn_mfma_f32_16x16x32_bf16(__builtin_bit_cast(bf16x8,G2), bs, a10, 0,0,0);
  f32x4 a11 = __builtin_amdgcn_mfma_f32_16x16x32_bf16(__builtin_bit_cast(bf16x8,G3), bh, z, 0,0,0);
  a11 = __builtin_amdgcn_mfma_f32_16x16x32_bf16(__builtin_bit_cast(bf16x8,G3), bs, a11, 0,0,0);
  #pragma unroll
  for (int i2 = 0; i2 < 4; ++i2)
    v[i2] = c00*a00[i2] + c01*a01[i2] + c10*a10[i2] + c11*a11[i2];
  make_bfrag(v, bfr);
}

__global__ __launch_bounds__(256, 2) void mps_chain(
  const float* __restrict__ phi,
  const float* __restrict__ core_first,
  const float* __restrict__ core_last,
  const float* __restrict__ bias,
  const i32x4* __restrict__ ws,
  float* __restrict__ out)
{
  const int lane = threadIdx.x & 63;
  const int wv   = threadIdx.x >> 6;
  const int n    = lane & 15;            // sample column within a group
  const int g    = lane >> 4;            // matrix row group / phi window quarter
  const bool isFwd = (wv < 2);
  const int dirIdx = isFwd ? 0 : 1;
  // wave covers 32 samples: 2 chains x 16
  const int sb   = blockIdx.x * 64 + (wv & 1) * 32;

  __shared__ float red[128*20];          // epilogue reduction only (10 KB)

  const i32x4* wsD    = isFwd ? ws : (ws + BWD_OFF);
  const int    maxPr  = isFwd ? NPF - 1 : NPB - 1;
  const i32x4* wsLane = wsD + lane;      // + pr*256 + f*64 selects (pair, combo)

  // phi window source base (lane map: sample = sb+16k+(lane&15),
  // window floats (lane>>4)*4 .. +3); chain k adds k*16*512 floats.
  const float* phiSrc0 = phi + (size_t)(sb + n) * 512 + g * 4;

  // ds_bpermute byte addrs: value(window float qt*4+e) lives in lane n+16*qt.
  const int qtF  = isFwd ? 0 : 1;
  const int aQ   = ((lane & 15) + 16*qtF) << 2;
  const int adrA0 = isFwd ? aQ       : aQ + 64;   // fwd fl2,3  | bwd fl10,11
  const int adrB0 = isFwd ? aQ + 64  : aQ + 128;  // fwd fl4,5  | bwd fl12,13
  const int adrA1 = isFwd ? aQ + 64  : aQ;        // fwd fl6,7  | bwd fl6,7
  const int adrB1 = isFwd ? aQ + 128 : aQ + 64;   // fwd fl8,9  | bwd fl8,9

  // ---- chain state: 2 independent chains ----
  float vch[2][4];
  i32x4 bfr[2];

  #pragma unroll
  for (int k = 0; k < 2; ++k){
    const float* pr = phi + (size_t)(sb + 16*k + n) * 512;
    if (isFwd){
      const float2 p0 = *(const float2*)pr;                 // phi[0]
      #pragma unroll
      for (int reg = 0; reg < 4; ++reg){
        const int r = g*4 + reg;
        vch[k][reg] = p0.x * core_first[r] + p0.y * core_first[16 + r];
      }
    } else {
      const float2 pL = *(const float2*)(pr + 510);         // phi[255]
      #pragma unroll
      for (int reg = 0; reg < 4; ++reg){
        const int r = g*4 + reg;
        vch[k][reg] = pL.x * core_last[2*r] + pL.y * core_last[2*r + 1];
      }
    }
    make_bfrag(vch[k], bfr[k]);
  }

  // ---- register prefetch state ----
  i32x4 GA0, GA1, GA2, GA3;   // even pair (2c)
  i32x4 GB0, GB1, GB2, GB3;   // odd pair (2c+1)
  f32x4 phiC[2], phiN[2];     // per-chain phi windows, chunks c and c+1

  { const i32x4* s = wsLane;        GA0=s[0]; GA1=s[64]; GA2=s[128]; GA3=s[192]; }
  { const i32x4* s = wsLane + 256;  GB0=s[0]; GB1=s[64]; GB2=s[128]; GB3=s[192]; }
  #pragma unroll
  for (int k = 0; k < 2; ++k){
    const float* ps = phiSrc0 + (size_t)k * 16 * 512;
    phiC[k] = *(const f32x4*)(ps + (isFwd ? 0 : 496));
    phiN[k] = *(const f32x4*)(ps + (isFwd ? 8 : 488));
  }
  __builtin_amdgcn_sched_barrier(0);

  #pragma unroll 1
  for (int c = 0; c < 32; ++c){
    // ---- chunk coefficients for both chains (cross-lane pulls) ----
    float2 cA0[2], cB0[2], cA1[2], cB1[2];
    #pragma unroll
    for (int k = 0; k < 2; ++k){
      #define SPULL(e, adr) __int_as_float(__builtin_amdgcn_ds_bpermute((adr), __float_as_int(phiC[k][e])))
      cA0[k] = make_float2(SPULL(2, adrA0), SPULL(3, adrA0));
      cB0[k] = make_float2(SPULL(0, adrB0), SPULL(1, adrB0));
      cA1[k] = make_float2(SPULL(2, adrA1), SPULL(3, adrA1));
      cB1[k] = make_float2(SPULL(0, adrB1), SPULL(1, adrB1));
      #undef SPULL
    }

    // ---- pair 2c: both chains share GA ----
    #pragma unroll
    for (int k = 0; k < 2; ++k)
      pair_step(GA0, GA1, GA2, GA3, cA0[k], cB0[k], vch[k], bfr[k]);
    { const int j = 2*c + 2;
      const i32x4* s = wsLane + (j > maxPr ? maxPr : j) * 256;
      GA0=s[0]; GA1=s[64]; GA2=s[128]; GA3=s[192]; }
    __builtin_amdgcn_sched_barrier(0);

    // ---- pair 2c+1: both chains share GB ----
    if (isFwd || (2*c + 1) < NPB){
      #pragma unroll
      for (int k = 0; k < 2; ++k)
        pair_step(GB0, GB1, GB2, GB3, cA1[k], cB1[k], vch[k], bfr[k]);
    }
    { const int j = 2*c + 3;
      const i32x4* s = wsLane + (j > maxPr ? maxPr : j) * 256;
      GB0=s[0]; GB1=s[64]; GB2=s[128]; GB3=s[192]; }

    // ---- phi rotate + prefetch chunk c+2 ----
    #pragma unroll
    for (int k = 0; k < 2; ++k) phiC[k] = phiN[k];
    { const int cc = (c + 2 > 31) ? 31 : (c + 2);
      #pragma unroll
      for (int k = 0; k < 2; ++k){
        const float* ps = phiSrc0 + (size_t)k * 16 * 512;
        phiN[k] = *(const f32x4*)(ps + (isFwd ? 8*cc : 496 - 8*cc));
      } }
    __builtin_amdgcn_sched_barrier(0);
  }

  // ---- epilogue: cross-wave reduction ----
  #pragma unroll
  for (int k = 0; k < 2; ++k)
    *(float4*)&red[(dirIdx*64 + (wv & 1)*32 + 16*k + n)*20 + 4*g] =
        make_float4(vch[k][0], vch[k][1], vch[k][2], vch[k][3]);
  __syncthreads();
  if (threadIdx.x < 64){
    const int s = threadIdx.x;
    float acc = bias[0];
    #pragma unroll
    for (int qq = 0; qq < 16; ++qq)
      acc += red[s*20 + qq] * red[(64 + s)*20 + qq];
    out[blockIdx.x*64 + s] = acc;
  }
}

extern "C" void kernel_launch(void* const* d_in, const int* in_sizes, int n_in,
                              void* d_out, int out_size, void* d_ws, size_t ws_size,
                              hipStream_t stream)
{
  const float* phi  = (const float*)d_in[0];  // [32768,256,2]
  const float* cf   = (const float*)d_in[1];  // [2,16]
  const float* cm   = (const float*)d_in[2];  // [254,16,2,16]
  const float* cl   = (const float*)d_in[3];  // [16,2]
  const float* bias = (const float*)d_in[4];  // scalar
  i32x4* ws = (i32x4*)d_ws;                   // (64+63)*4*64*16B = 508 KB

  build_pair_frags<<<NPF + NPB, 256, 0, stream>>>(cm, ws);
  mps_chain<<<512, 256, 0, stream>>>(phi, cf, cl, bias, ws, (float*)d_out);
}